// Round 8
// baseline (964.805 us; speedup 1.0000x reference)
//
#include <hip/hip_runtime.h>

#define N_M 100000
#define N_D 30000
#define N_A 80000

// source-chunk binning: kept in the SORT and now USED again by the gather
// kernels as chunk-phases (2 MB t-window + 1 MB y-window fits per-XCD L2).
#define CSHIFT 14
#define NC_M 7   // ceil(100000/16384)
#define NC_D 2   // ceil(30000/16384)
#define NC_A 5   // ceil(80000/16384)

// global bin layout: [md: N_D*NC_M | dm: N_M*NC_D | ma: N_A*NC_M | am: N_M*NC_A]
#define BO_MD 0
#define BO_DM (BO_MD + N_D * NC_M)   // 210000
#define BO_MA (BO_DM + N_M * NC_D)   // 410000
#define BO_AM (BO_MA + N_A * NC_M)   // 970000
#define B_TOT (BO_AM + N_M * NC_A)   // 1470000

// 2-level MSD sort: coarse bucket = key>>12 (359 buckets), fine digit = key&4095
#define FBITS 12
#define NFINE 4096
#define NBUCK ((B_TOT + NFINE - 1) / NFINE)   // 359
#define T_A 4096                              // edges per phase-A block

typedef unsigned int u32;
typedef unsigned short u16;
typedef unsigned long long u64;

__device__ __forceinline__ u16 f2bf(float f) {
  u32 u = __float_as_uint(f);
  return (u16)((u + 0x7FFFu + ((u >> 16) & 1u)) >> 16);
}
__device__ __forceinline__ float bf2f(u16 b) {
  return __uint_as_float(((u32)b) << 16);
}
__device__ __forceinline__ float bf2f_hi(u32 v) {
  return __uint_as_float(v & 0xFFFF0000u);
}
// packed edge: src[31:15] (src<131072), bf16(ew) sans sign in [14:0] (ew>=0)
__device__ __forceinline__ u32 pack_edge(int src, float ew) {
  return ((u32)src << 15) | ((u32)f2bf(ew) & 0x7FFFu);
}

// ===========================================================================
// Bin build: contiguous-write 2-level counting sort (unchanged)
// ===========================================================================
struct Rel { const int* src; const int* dst; const float* ew; int nE; int binBase; int nC; };
struct Rel4 { Rel r[4]; int blkStart[5]; };

__global__ __launch_bounds__(256) void phase0(Rel4 P, int* __restrict__ bucketHist) {
  __shared__ u32 lh[512];
  int tid = threadIdx.x;
  int b = blockIdx.x, s = 0;
  while (b >= P.blkStart[s + 1]) s++;
  const Rel R = P.r[s];
  int base = (b - P.blkStart[s]) * T_A;
  for (int i = tid; i < 512; i += 256) lh[i] = 0;
  __syncthreads();
#pragma unroll 4
  for (int k = 0; k < 16; k++) {
    int e = base + tid + k * 256;
    if (e < R.nE) {
      int key = R.binBase + R.dst[e] * R.nC + (R.src[e] >> CSHIFT);
      atomicAdd(&lh[key >> FBITS], 1u);
    }
  }
  __syncthreads();
  for (int i = tid; i < 512; i += 256) if (lh[i]) atomicAdd(&bucketHist[i], (int)lh[i]);
}

__global__ __launch_bounds__(256) void scan_bucket(const int* __restrict__ bucketHist,
                                                   int* __restrict__ bucketBase,
                                                   int* __restrict__ cursor) {
  __shared__ int wsum[4];
  int tid = threadIdx.x;
  int j0 = tid * 2;
  int a0 = (j0 < NBUCK) ? bucketHist[j0] : 0;
  int a1 = (j0 + 1 < NBUCK) ? bucketHist[j0 + 1] : 0;
  int ssum = a0 + a1;
  int lane = tid & 63, wid = tid >> 6;
  int sc = ssum;
#pragma unroll
  for (int off = 1; off < 64; off <<= 1) { int t = __shfl_up(sc, off, 64); if (lane >= off) sc += t; }
  if (lane == 63) wsum[wid] = sc;
  __syncthreads();
  int wex = 0, tot = 0;
  for (int w = 0; w < 4; w++) { int t = wsum[w]; if (w < wid) wex += t; tot += t; }
  int ex = wex + sc - ssum;
  if (j0 < NBUCK) { bucketBase[j0] = ex; cursor[j0] = ex; }
  if (j0 + 1 < NBUCK) { bucketBase[j0 + 1] = ex + a0; cursor[j0 + 1] = ex + a0; }
  if (tid == 0) bucketBase[NBUCK] = tot;
}

__global__ __launch_bounds__(256) void phaseA(Rel4 P, int* __restrict__ cursor,
                                              u64* __restrict__ tmp) {
  __shared__ u32 hist[512], lstart[512], cur[512], gbase[512];
  __shared__ u64 stage[T_A];
  __shared__ u32 wsum[4];
  int tid = threadIdx.x;
  int b = blockIdx.x, s = 0;
  while (b >= P.blkStart[s + 1]) s++;
  const Rel R = P.r[s];
  int base = (b - P.blkStart[s]) * T_A;
  int valid = min(T_A, R.nE - base);
  for (int i = tid; i < 512; i += 256) hist[i] = 0;
  __syncthreads();
#pragma unroll 4
  for (int k = 0; k < 16; k++) {
    int e = base + tid + k * 256;
    if (e < R.nE) {
      int key = R.binBase + R.dst[e] * R.nC + (R.src[e] >> CSHIFT);
      atomicAdd(&hist[key >> FBITS], 1u);
    }
  }
  __syncthreads();
  int c0 = tid * 2;
  u32 h0 = hist[c0], h1 = hist[c0 + 1];
  u32 ssum = h0 + h1;
  int lane = tid & 63, wid = tid >> 6;
  u32 sc = ssum;
#pragma unroll
  for (int off = 1; off < 64; off <<= 1) { int t = __shfl_up((int)sc, off, 64); if (lane >= off) sc += (u32)t; }
  if (lane == 63) wsum[wid] = sc;
  __syncthreads();
  u32 wex = 0;
  for (int w = 0; w < 4; w++) if (w < wid) wex += wsum[w];
  u32 ex = wex + sc - ssum;
  lstart[c0] = ex;       cur[c0] = ex;
  lstart[c0 + 1] = ex + h0; cur[c0 + 1] = ex + h0;
  if (h0) gbase[c0] = (u32)atomicAdd(&cursor[c0], (int)h0);
  if (h1) gbase[c0 + 1] = (u32)atomicAdd(&cursor[c0 + 1], (int)h1);
  __syncthreads();
#pragma unroll 4
  for (int k = 0; k < 16; k++) {
    int e = base + tid + k * 256;
    if (e < R.nE) {
      int srcv = R.src[e];
      int key = R.binBase + R.dst[e] * R.nC + (srcv >> CSHIFT);
      u32 slot = atomicAdd(&cur[key >> FBITS], 1u);
      stage[slot] = ((u64)(u32)key << 32) | pack_edge(srcv, R.ew[e]);
    }
  }
  __syncthreads();
  for (int i = tid; i < valid; i += 256) {
    u64 v = stage[i];
    u32 c = (u32)(v >> (32 + FBITS));
    tmp[gbase[c] + ((u32)i - lstart[c])] = v;
  }
}

__global__ __launch_bounds__(256) void phaseB(const u64* __restrict__ tmp,
                                              const int* __restrict__ bucketBase,
                                              u32* __restrict__ pairs,
                                              int* __restrict__ bins) {
  __shared__ u32 h2[NFINE], cur2[NFINE];
  __shared__ u32 wsum[4];
  int c = blockIdx.x, tid = threadIdx.x;
  int s0 = bucketBase[c], s1 = bucketBase[c + 1];
  for (int i = tid; i < NFINE; i += 256) h2[i] = 0;
  __syncthreads();
  for (int e = s0 + tid; e < s1; e += 256) {
    u32 fine = (u32)(tmp[e] >> 32) & (NFINE - 1);
    atomicAdd(&h2[fine], 1u);
  }
  __syncthreads();
  int f0 = tid * 16;
  u32 v[16], ssum = 0;
#pragma unroll
  for (int i = 0; i < 16; i++) { v[i] = h2[f0 + i]; ssum += v[i]; }
  int lane = tid & 63, wid = tid >> 6;
  u32 sc = ssum;
#pragma unroll
  for (int off = 1; off < 64; off <<= 1) { int t = __shfl_up((int)sc, off, 64); if (lane >= off) sc += (u32)t; }
  if (lane == 63) wsum[wid] = sc;
  __syncthreads();
  u32 wex = 0;
  for (int w = 0; w < 4; w++) if (w < wid) wex += wsum[w];
  u32 ex = wex + sc - ssum;
  int binBase0 = c << FBITS;
#pragma unroll
  for (int i = 0; i < 16; i++) {
    int gb = binBase0 + f0 + i;
    if (gb < B_TOT) bins[gb] = s0 + (int)ex;
    cur2[f0 + i] = ex;
    ex += v[i];
  }
  if (c == NBUCK - 1 && tid == 0) bins[B_TOT] = s1;
  __syncthreads();
  for (int e = s0 + tid; e < s1; e += 256) {
    u64 t = tmp[e];
    u32 fine = (u32)(t >> 32) & (NFINE - 1);
    u32 pos = atomicAdd(&cur2[fine], 1u);
    pairs[s0 + pos] = (u32)t;
  }
}

// ===========================================================================
// Layer-1 dense transforms (unchanged from R7)
// ===========================================================================
__global__ __launch_bounds__(256) void l1_tr_m(
    const float* __restrict__ x,
    const float* __restrict__ Wr0, const float* __restrict__ Wr2,
    const float* __restrict__ Wt1, const float* __restrict__ Wt3,
    const float* __restrict__ b1a, const float* __restrict__ b1b,
    u16* __restrict__ t0, u16* __restrict__ t2, u16* __restrict__ r, int n) {
  __shared__ float A[4096], B[4096], C[4096];
  for (int i = threadIdx.x * 4; i < 4096; i += 1024) {
    *(float4*)&A[i] = *(const float4*)&Wr0[i];
    *(float4*)&B[i] = *(const float4*)&Wr2[i];
    float4 p = *(const float4*)&Wt1[i], q = *(const float4*)&Wt3[i];
    *(float4*)&C[i] = make_float4(p.x + q.x, p.y + q.y, p.z + q.z, p.w + q.w);
  }
  __syncthreads();
  int lane = threadIdx.x & 63, wid = threadIdx.x >> 6;
  int wave = blockIdx.x * 4 + wid, nW = gridDim.x * 4;
  float bj = b1a[lane] + b1b[lane];
  for (int base = wave * 4; base < n; base += nW * 4) {
    int n0 = base, n1 = min(base + 1, n - 1), n2 = min(base + 2, n - 1), n3 = min(base + 3, n - 1);
    float o0a = 0, o0b = 0, o0c = bj, o1a = 0, o1b = 0, o1c = bj;
    float o2a = 0, o2b = 0, o2c = bj, o3a = 0, o3b = 0, o3c = bj;
#pragma unroll 4
    for (int k = 0; k < 64; k++) {
      float wa = A[k * 64 + lane], wb = B[k * 64 + lane], wc = C[k * 64 + lane];
      float x0 = x[(size_t)n0 * 64 + k], x1 = x[(size_t)n1 * 64 + k];
      float x2 = x[(size_t)n2 * 64 + k], x3 = x[(size_t)n3 * 64 + k];
      o0a = fmaf(x0, wa, o0a); o0b = fmaf(x0, wb, o0b); o0c = fmaf(x0, wc, o0c);
      o1a = fmaf(x1, wa, o1a); o1b = fmaf(x1, wb, o1b); o1c = fmaf(x1, wc, o1c);
      o2a = fmaf(x2, wa, o2a); o2b = fmaf(x2, wb, o2b); o2c = fmaf(x2, wc, o2c);
      o3a = fmaf(x3, wa, o3a); o3b = fmaf(x3, wb, o3b); o3c = fmaf(x3, wc, o3c);
    }
    t0[(size_t)n0 * 64 + lane] = f2bf(o0a); t2[(size_t)n0 * 64 + lane] = f2bf(o0b); r[(size_t)n0 * 64 + lane] = f2bf(o0c);
    if (base + 1 < n) { t0[(size_t)n1 * 64 + lane] = f2bf(o1a); t2[(size_t)n1 * 64 + lane] = f2bf(o1b); r[(size_t)n1 * 64 + lane] = f2bf(o1c); }
    if (base + 2 < n) { t0[(size_t)n2 * 64 + lane] = f2bf(o2a); t2[(size_t)n2 * 64 + lane] = f2bf(o2b); r[(size_t)n2 * 64 + lane] = f2bf(o2c); }
    if (base + 3 < n) { t0[(size_t)n3 * 64 + lane] = f2bf(o3a); t2[(size_t)n3 * 64 + lane] = f2bf(o3b); r[(size_t)n3 * 64 + lane] = f2bf(o3c); }
  }
}

__global__ __launch_bounds__(256) void l1_tr_s2(
    const float* __restrict__ x1, const float* __restrict__ Wrel1,
    const float* __restrict__ Wroot1, const float* __restrict__ bias1,
    u16* __restrict__ t1o, u16* __restrict__ r1o, int n1, int nBlk1,
    const float* __restrict__ x2, const float* __restrict__ Wrel2,
    const float* __restrict__ Wroot2, const float* __restrict__ bias2,
    u16* __restrict__ t2o, u16* __restrict__ r2o, int n2) {
  __shared__ float A[4096], C[4096];
  bool first = (int)blockIdx.x < nBlk1;
  const float* x = first ? x1 : x2;
  const float* Wrel = first ? Wrel1 : Wrel2;
  const float* Wroot = first ? Wroot1 : Wroot2;
  const float* bias = first ? bias1 : bias2;
  u16* t = first ? t1o : t2o;
  u16* r = first ? r1o : r2o;
  int n = first ? n1 : n2;
  int blk = first ? blockIdx.x : blockIdx.x - nBlk1;
  int nBlk = first ? nBlk1 : (gridDim.x - nBlk1);
  for (int i = threadIdx.x * 4; i < 4096; i += 1024) {
    *(float4*)&A[i] = *(const float4*)&Wrel[i];
    *(float4*)&C[i] = *(const float4*)&Wroot[i];
  }
  __syncthreads();
  int lane = threadIdx.x & 63, wid = threadIdx.x >> 6;
  int wave = blk * 4 + wid, nW = nBlk * 4;
  float bj = bias[lane];
  for (int base = wave * 4; base < n; base += nW * 4) {
    int n0 = base, n1_ = min(base + 1, n - 1), n2_ = min(base + 2, n - 1), n3_ = min(base + 3, n - 1);
    float o0a = 0, o0c = bj, o1a = 0, o1c = bj, o2a = 0, o2c = bj, o3a = 0, o3c = bj;
#pragma unroll 4
    for (int k = 0; k < 64; k++) {
      float wa = A[k * 64 + lane], wc = C[k * 64 + lane];
      float x0 = x[(size_t)n0 * 64 + k], xx1 = x[(size_t)n1_ * 64 + k];
      float xx2 = x[(size_t)n2_ * 64 + k], xx3 = x[(size_t)n3_ * 64 + k];
      o0a = fmaf(x0, wa, o0a); o0c = fmaf(x0, wc, o0c);
      o1a = fmaf(xx1, wa, o1a); o1c = fmaf(xx1, wc, o1c);
      o2a = fmaf(xx2, wa, o2a); o2c = fmaf(xx2, wc, o2c);
      o3a = fmaf(xx3, wa, o3a); o3c = fmaf(xx3, wc, o3c);
    }
    t[(size_t)n0 * 64 + lane] = f2bf(o0a); r[(size_t)n0 * 64 + lane] = f2bf(o0c);
    if (base + 1 < n) { t[(size_t)n1_ * 64 + lane] = f2bf(o1a); r[(size_t)n1_ * 64 + lane] = f2bf(o1c); }
    if (base + 2 < n) { t[(size_t)n2_ * 64 + lane] = f2bf(o2a); r[(size_t)n2_ * 64 + lane] = f2bf(o2c); }
    if (base + 3 < n) { t[(size_t)n3_ * 64 + lane] = f2bf(o3a); r[(size_t)n3_ * 64 + lane] = f2bf(o3c); }
  }
}

// ===========================================================================
// Gather bodies (R7, unchanged): 8-edge unroll, XOR/diff routing, zero-pad
// tails via pb = pa & ~0x7FFF.
// ===========================================================================
__device__ __forceinline__ void g2_pair(u32 pa, u32 pb,
    const u16* __restrict__ tbl, u32 lanebyte, u32 hm,
    float& a0, float& a1) {
  u32 offa = (pa >> 15) << 7, offd = ((pb >> 15) << 7) - offa;
  u32 wa = (pa & 0x7FFFu) << 16, wd = ((pb & 0x7FFFu) << 16) ^ wa;
  u32 v = *(const u32*)((const char*)tbl + ((hm & offd) + offa + lanebyte));
  float w = __uint_as_float((hm & wd) ^ wa);
  a0 = fmaf(w, bf2f((u16)v), a0);
  a1 = fmaf(w, bf2f_hi(v), a1);
}

__device__ __forceinline__ void g2y_pair(u32 pa, u32 pb,
    const u16* __restrict__ tbl, const u16* __restrict__ ytbl,
    u32 lanebyte, u32 ylanebyte, u32 hm,
    float& a0, float& a1, float& ay) {
  u32 ra = pa >> 15, rb = pb >> 15;
  u32 offa = ra << 7, offd = (rb << 7) - offa;
  u32 yoa = ra << 6,  yod = (rb << 6) - yoa;
  u32 wa = (pa & 0x7FFFu) << 16, wd = ((pb & 0x7FFFu) << 16) ^ wa;
  u32 v = *(const u32*)((const char*)tbl + ((hm & offd) + offa + lanebyte));
  u16 q = *(const u16*)((const char*)ytbl + ((hm & yod) + yoa + ylanebyte));
  float w = __uint_as_float((hm & wd) ^ wa);
  a0 = fmaf(w, bf2f((u16)v), a0);
  a1 = fmaf(w, bf2f_hi(v), a1);
  ay = fmaf(w, bf2f(q), ay);
}

#define RL(x, i) ((u32)__builtin_amdgcn_readlane((int)(x), (i)))

__device__ __forceinline__ void gather2_seg64(
    int s0, int s1, const u32* __restrict__ pairs,
    const u16* __restrict__ tbl, u32 lanebyte, u32 hm, int lane, u32 pw0,
    float& a0, float& a1) {
  int base = s0;
  u32 pw = pw0;
  for (;;) {
    int cnt = s1 - base; if (cnt > 64) cnt = 64;
    int e = 0;
    for (; e + 8 <= cnt; e += 8) {
      u32 p0 = RL(pw, e),     p1 = RL(pw, e + 1), p2 = RL(pw, e + 2), p3 = RL(pw, e + 3);
      u32 p4 = RL(pw, e + 4), p5 = RL(pw, e + 5), p6 = RL(pw, e + 6), p7 = RL(pw, e + 7);
      g2_pair(p0, p1, tbl, lanebyte, hm, a0, a1);
      g2_pair(p2, p3, tbl, lanebyte, hm, a0, a1);
      g2_pair(p4, p5, tbl, lanebyte, hm, a0, a1);
      g2_pair(p6, p7, tbl, lanebyte, hm, a0, a1);
    }
    if (e + 4 <= cnt) {
      u32 p0 = RL(pw, e), p1 = RL(pw, e + 1), p2 = RL(pw, e + 2), p3 = RL(pw, e + 3);
      g2_pair(p0, p1, tbl, lanebyte, hm, a0, a1);
      g2_pair(p2, p3, tbl, lanebyte, hm, a0, a1);
      e += 4;
    }
    if (e + 2 <= cnt) {
      u32 p0 = RL(pw, e), p1 = RL(pw, e + 1);
      g2_pair(p0, p1, tbl, lanebyte, hm, a0, a1);
      e += 2;
    }
    if (e < cnt) {
      u32 p = RL(pw, e);
      g2_pair(p, p & 0xFFFF8000u, tbl, lanebyte, hm, a0, a1);
    }
    base += 64;
    if (base >= s1) break;
    pw = (base + lane < s1) ? pairs[base + lane] : 0u;
  }
}

__device__ __forceinline__ void gather2y_seg64(
    int s0, int s1, const u32* __restrict__ pairs,
    const u16* __restrict__ tbl, const u16* __restrict__ ytbl,
    u32 lanebyte, u32 ylanebyte, u32 hm, int lane, u32 pw0,
    float& a0, float& a1, float& ay) {
  int base = s0;
  u32 pw = pw0;
  for (;;) {
    int cnt = s1 - base; if (cnt > 64) cnt = 64;
    int e = 0;
    for (; e + 8 <= cnt; e += 8) {
      u32 p0 = RL(pw, e),     p1 = RL(pw, e + 1), p2 = RL(pw, e + 2), p3 = RL(pw, e + 3);
      u32 p4 = RL(pw, e + 4), p5 = RL(pw, e + 5), p6 = RL(pw, e + 6), p7 = RL(pw, e + 7);
      g2y_pair(p0, p1, tbl, ytbl, lanebyte, ylanebyte, hm, a0, a1, ay);
      g2y_pair(p2, p3, tbl, ytbl, lanebyte, ylanebyte, hm, a0, a1, ay);
      g2y_pair(p4, p5, tbl, ytbl, lanebyte, ylanebyte, hm, a0, a1, ay);
      g2y_pair(p6, p7, tbl, ytbl, lanebyte, ylanebyte, hm, a0, a1, ay);
    }
    if (e + 4 <= cnt) {
      u32 p0 = RL(pw, e), p1 = RL(pw, e + 1), p2 = RL(pw, e + 2), p3 = RL(pw, e + 3);
      g2y_pair(p0, p1, tbl, ytbl, lanebyte, ylanebyte, hm, a0, a1, ay);
      g2y_pair(p2, p3, tbl, ytbl, lanebyte, ylanebyte, hm, a0, a1, ay);
      e += 4;
    }
    if (e + 2 <= cnt) {
      u32 p0 = RL(pw, e), p1 = RL(pw, e + 1);
      g2y_pair(p0, p1, tbl, ytbl, lanebyte, ylanebyte, hm, a0, a1, ay);
      e += 2;
    }
    if (e < cnt) {
      u32 p = RL(pw, e);
      g2y_pair(p, p & 0xFFFF8000u, tbl, ytbl, lanebyte, ylanebyte, hm, a0, a1, ay);
    }
    base += 64;
    if (base >= s1) break;
    pw = (base + lane < s1) ? pairs[base + lane] : 0u;
  }
}

// ===========================================================================
// 32-wide gather (outm only): unchanged.
// ===========================================================================
__device__ __forceinline__ void gathero_32(
    int s0, int s1, const u32* __restrict__ pairs,
    const u16* __restrict__ ytbl, int lanebyte, int oaddr, int lane,
    float& a0, float& a1, float& a2, float& a3) {
  for (int base = s0; base < s1; base += 64) {
    u32 pw = 0;
    if (base + lane < s1) pw = pairs[base + lane];
    int ng = min(s1 - base, 64);
    ng = (ng + 7) >> 3;
#pragma unroll 2
    for (int g = 0; g < ng; g++) {
      u32 p = (u32)__builtin_amdgcn_ds_bpermute(oaddr + (g << 5), (int)pw);
      u32 off = ((p >> 15) << 6) + lanebyte;
      float w = __uint_as_float((p & 0x7FFFu) << 16);
      uint2 v = *(const uint2*)((const char*)ytbl + off);
      a0 = fmaf(w, bf2f((u16)v.x), a0);
      a1 = fmaf(w, bf2f_hi(v.x), a1);
      a2 = fmaf(w, bf2f((u16)v.y), a2);
      a3 = fmaf(w, bf2f_hi(v.y), a3);
    }
  }
}

// Merged fused1 (single side per dispatch, chunk-phased): per chunk c, the
// block's working set is a 2 MB t-window + 1 MB y-window (fits per-XCD L2).
// Boundary VGPR holds all 8*NC_M+1 = 57 chunk boundaries for the wave.
__global__ __launch_bounds__(512) void fused1(
    const int* __restrict__ bins, const u32* __restrict__ pairs,
    const u16* __restrict__ tbl, const u16* __restrict__ ytbl,
    const u16* __restrict__ r1,
    const float* __restrict__ W2r, const float* __restrict__ W2t,
    const float* __restrict__ b2s,
    u16* __restrict__ y, float* __restrict__ out,
    int n, int binBase) {
  __shared__ float Wy[2048], Wt[2048];
  __shared__ float bs[32];
  __shared__ __align__(16) float scr[8][64];
  for (int i = threadIdx.x; i < 2048; i += 512) { Wy[i] = W2r[i]; Wt[i] = W2t[i]; }
  if (threadIdx.x < 32) bs[threadIdx.x] = b2s[threadIdx.x];
  __syncthreads();
  int lane = threadIdx.x & 63, wid = threadIdx.x >> 6;
  int j = lane & 31, half = lane >> 5;
  u32 lanebyte = (u32)j << 2;
  u32 ylanebyte = (u32)j << 1;
  u32 hm = half ? 0xFFFFFFFFu : 0u;
  int node0 = (blockIdx.x * 8 + wid) * 8;
  int bidx = min(node0 * NC_M + min(lane, 8 * NC_M), n * NC_M);
  int bnd = bins[binBase + bidx];
  float acc0[8], acc1[8], accy[8];
#pragma unroll
  for (int i = 0; i < 8; i++) { acc0[i] = 0.f; acc1[i] = 0.f; accy[i] = 0.f; }
  for (int c = 0; c < NC_M; c++) {
    // batched first-window pair prefetch for this chunk-phase (8 loads in flight)
    u32 pwp[8];
#pragma unroll
    for (int i = 0; i < 8; i++) {
      int s0 = __builtin_amdgcn_readlane(bnd, i * NC_M + c);
      int s1 = __builtin_amdgcn_readlane(bnd, i * NC_M + c + 1);
      pwp[i] = (node0 + i < n && s0 + lane < s1) ? pairs[s0 + lane] : 0u;
    }
#pragma unroll
    for (int i = 0; i < 8; i++) {
      int s0 = __builtin_amdgcn_readlane(bnd, i * NC_M + c);
      int s1 = __builtin_amdgcn_readlane(bnd, i * NC_M + c + 1);
      if (node0 + i < n && s0 < s1)
        gather2y_seg64(s0, s1, pairs, tbl, ytbl, lanebyte, ylanebyte, hm, lane, pwp[i],
                       acc0[i], acc1[i], accy[i]);
    }
  }
#pragma unroll
  for (int i = 0; i < 8; i++) {
    int node = node0 + i;
    if (node >= n) continue;
    float a0 = acc0[i] + __shfl_xor(acc0[i], 32);
    float a1 = acc1[i] + __shfl_xor(acc1[i], 32);
    float ayt = accy[i] + __shfl_xor(accy[i], 32);
    u32 rv = *(const u32*)&r1[(size_t)node * 64 + 2 * j];
    float hv0 = fmaxf(a0 + bf2f((u16)rv), 0.f);
    float hv1 = fmaxf(a1 + bf2f_hi(rv), 0.f);
    if (!half) *(float2*)&scr[wid][2 * j] = make_float2(hv0, hv1);
    float oy = 0.f, ot = 0.f;
#pragma unroll
    for (int kk = 0; kk < 32; kk++) {
      int k = (half << 5) + kk;
      float s = scr[wid][k];
      oy = fmaf(s, Wy[k * 32 + j], oy);
      ot = fmaf(s, Wt[k * 32 + j], ot);
    }
    oy += __shfl_xor(oy, 32);
    ot += __shfl_xor(ot, 32);
    if (lane < 32) {
      y[(size_t)node * 32 + lane] = f2bf(oy);
      out[(size_t)node * 32 + lane] = ot + bs[lane] + ayt;
    }
  }
}

// Movie variant: dm side merged (t_dm 3.8 MB ~ L2-resident), am side
// chunk-phased (t_am 10 MB, 25x reuse). Runs FIRST.
__global__ __launch_bounds__(512) void fusedm(
    const int* __restrict__ bins, const u32* __restrict__ pairs,
    const u16* __restrict__ tbl1,   // t_dm (director rows)
    const u16* __restrict__ tbl2,   // t_am (actor rows)
    const u16* __restrict__ r1,
    const float* __restrict__ W2r0, const float* __restrict__ W2r2,
    const float* __restrict__ W2t1, const float* __restrict__ W2t3,
    const float* __restrict__ b2a, const float* __restrict__ b2b,
    u16* __restrict__ y0, u16* __restrict__ y2, float* __restrict__ oroot, int n) {
  __shared__ float Wy0[2048], Wy2[2048], Wt[2048];
  __shared__ float bs[32];
  __shared__ __align__(16) float scr[8][64];
  for (int i = threadIdx.x; i < 2048; i += 512) {
    Wy0[i] = W2r0[i]; Wy2[i] = W2r2[i]; Wt[i] = W2t1[i] + W2t3[i];
  }
  if (threadIdx.x < 32) bs[threadIdx.x] = b2a[threadIdx.x] + b2b[threadIdx.x];
  __syncthreads();
  int lane = threadIdx.x & 63, wid = threadIdx.x >> 6;
  int j = lane & 31, half = lane >> 5;
  u32 lanebyte = (u32)j << 2;
  u32 hm = half ? 0xFFFFFFFFu : 0u;
  int node0 = (blockIdx.x * 8 + wid) * 8;
  int bdm = bins[BO_DM + min(node0 + min(lane, 8), n) * NC_D];
  int baidx = min(node0 * NC_A + min(lane, 8 * NC_A), n * NC_A);
  int bam = bins[BO_AM + baidx];
  float acc0[8], acc1[8];
#pragma unroll
  for (int i = 0; i < 8; i++) { acc0[i] = 0.f; acc1[i] = 0.f; }
  // dm side: merged full segments
  {
    u32 pwp[8];
#pragma unroll
    for (int i = 0; i < 8; i++) {
      int s0 = __builtin_amdgcn_readlane(bdm, i);
      int s1 = __builtin_amdgcn_readlane(bdm, i + 1);
      pwp[i] = (node0 + i < n && s0 + lane < s1) ? pairs[s0 + lane] : 0u;
    }
#pragma unroll
    for (int i = 0; i < 8; i++) {
      int s0 = __builtin_amdgcn_readlane(bdm, i);
      int s1 = __builtin_amdgcn_readlane(bdm, i + 1);
      if (node0 + i < n && s0 < s1)
        gather2_seg64(s0, s1, pairs, tbl1, lanebyte, hm, lane, pwp[i], acc0[i], acc1[i]);
    }
  }
  // am side: chunk-phased
  for (int c = 0; c < NC_A; c++) {
    u32 pwp[8];
#pragma unroll
    for (int i = 0; i < 8; i++) {
      int s0 = __builtin_amdgcn_readlane(bam, i * NC_A + c);
      int s1 = __builtin_amdgcn_readlane(bam, i * NC_A + c + 1);
      pwp[i] = (node0 + i < n && s0 + lane < s1) ? pairs[s0 + lane] : 0u;
    }
#pragma unroll
    for (int i = 0; i < 8; i++) {
      int s0 = __builtin_amdgcn_readlane(bam, i * NC_A + c);
      int s1 = __builtin_amdgcn_readlane(bam, i * NC_A + c + 1);
      if (node0 + i < n && s0 < s1)
        gather2_seg64(s0, s1, pairs, tbl2, lanebyte, hm, lane, pwp[i], acc0[i], acc1[i]);
    }
  }
#pragma unroll
  for (int i = 0; i < 8; i++) {
    int node = node0 + i;
    if (node >= n) continue;
    float a0 = acc0[i] + __shfl_xor(acc0[i], 32);
    float a1 = acc1[i] + __shfl_xor(acc1[i], 32);
    u32 rv = *(const u32*)&r1[(size_t)node * 64 + 2 * j];
    float hv0 = fmaxf(a0 + bf2f((u16)rv), 0.f);
    float hv1 = fmaxf(a1 + bf2f_hi(rv), 0.f);
    if (!half) *(float2*)&scr[wid][2 * j] = make_float2(hv0, hv1);
    float o0 = 0.f, o2 = 0.f, ot = 0.f;
#pragma unroll
    for (int kk = 0; kk < 32; kk++) {
      int k = (half << 5) + kk;
      float s = scr[wid][k];
      o0 = fmaf(s, Wy0[k * 32 + j], o0);
      o2 = fmaf(s, Wy2[k * 32 + j], o2);
      ot = fmaf(s, Wt[k * 32 + j], ot);
    }
    o0 += __shfl_xor(o0, 32);
    o2 += __shfl_xor(o2, 32);
    ot += __shfl_xor(ot, 32);
    if (lane < 32) {
      y0[(size_t)node * 32 + lane] = f2bf(o0);
      y2[(size_t)node * 32 + lane] = f2bf(o2);
      oroot[(size_t)node * 32 + lane] = ot + bs[lane];
    }
  }
}

__global__ __launch_bounds__(256) void outm(
    const int* __restrict__ bins, const u32* __restrict__ pairs,
    const u16* __restrict__ y1,   // y_dm (director rows)
    const u16* __restrict__ y2,   // y_am (actor rows)
    float* __restrict__ out, int n) {
  int lane = threadIdx.x & 63, wid = threadIdx.x >> 6;
  int node0 = (blockIdx.x * 4 + wid) * 8;
  int j8 = lane & 7;
  int lanebyte = j8 << 3;
  int oaddr = (lane >> 3) << 2;
  int bdm = bins[BO_DM + min(node0 + min(lane, 8), n) * NC_D];
  int bam = bins[BO_AM + min(node0 + min(lane, 8), n) * NC_A];
  float acc0[8], acc1[8], acc2[8], acc3[8];
#pragma unroll
  for (int i = 0; i < 8; i++) { acc0[i] = 0.f; acc1[i] = 0.f; acc2[i] = 0.f; acc3[i] = 0.f; }
#pragma unroll
  for (int i = 0; i < 8; i++) {
    int s0 = __builtin_amdgcn_readlane(bdm, i);
    int s1 = __builtin_amdgcn_readlane(bdm, i + 1);
    if (node0 + i < n) gathero_32(s0, s1, pairs, y1, lanebyte, oaddr, lane,
                                  acc0[i], acc1[i], acc2[i], acc3[i]);
  }
#pragma unroll
  for (int i = 0; i < 8; i++) {
    int s0 = __builtin_amdgcn_readlane(bam, i);
    int s1 = __builtin_amdgcn_readlane(bam, i + 1);
    if (node0 + i < n) gathero_32(s0, s1, pairs, y2, lanebyte, oaddr, lane,
                                  acc0[i], acc1[i], acc2[i], acc3[i]);
  }
#pragma unroll
  for (int i = 0; i < 8; i++) {
    int node = node0 + i;
    if (node >= n) continue;
    float a0 = acc0[i], a1 = acc1[i], a2 = acc2[i], a3 = acc3[i];
    a0 += __shfl_xor(a0, 8); a0 += __shfl_xor(a0, 16); a0 += __shfl_xor(a0, 32);
    a1 += __shfl_xor(a1, 8); a1 += __shfl_xor(a1, 16); a1 += __shfl_xor(a1, 32);
    a2 += __shfl_xor(a2, 8); a2 += __shfl_xor(a2, 16); a2 += __shfl_xor(a2, 32);
    a3 += __shfl_xor(a3, 8); a3 += __shfl_xor(a3, 16); a3 += __shfl_xor(a3, 32);
    if (lane < 8) {
      float4* o = (float4*)((char*)out + (size_t)node * 128 + (j8 << 4));
      float4 v = *o;
      v.x += a0; v.y += a1; v.z += a2; v.w += a3;
      *o = v;
    }
  }
}

static inline int nblkA(long long e) { return (int)((e + T_A - 1) / T_A); }

extern "C" void kernel_launch(void* const* d_in, const int* in_sizes, int n_in,
                              void* d_out, int out_size, void* d_ws, size_t ws_size,
                              hipStream_t stream) {
  const float* x_m = (const float*)d_in[0];
  const float* x_d = (const float*)d_in[1];
  const float* x_a = (const float*)d_in[2];
  const int* src_md = (const int*)d_in[3];
  const int* dst_md = (const int*)d_in[4];
  const float* ew_md = (const float*)d_in[5];
  const int* src_dm = (const int*)d_in[6];
  const int* dst_dm = (const int*)d_in[7];
  const float* ew_dm = (const float*)d_in[8];
  const int* src_ma = (const int*)d_in[9];
  const int* dst_ma = (const int*)d_in[10];
  const float* ew_ma = (const float*)d_in[11];
  const int* src_am = (const int*)d_in[12];
  const int* dst_am = (const int*)d_in[13];
  const float* ew_am = (const float*)d_in[14];
  const float* W1_rel = (const float*)d_in[15];
  const float* b1 = (const float*)d_in[16];
  const float* W1_root = (const float*)d_in[17];
  const float* W2_rel = (const float*)d_in[18];
  const float* b2 = (const float*)d_in[19];
  const float* W2_root = (const float*)d_in[20];

  const int E_md = in_sizes[3];
  const int E_dm = in_sizes[6];
  const int E_ma = in_sizes[9];
  const int E_am = in_sizes[12];
  const long long E_tot = (long long)E_md + E_dm + E_ma + E_am;

  // ---- workspace ----
  char* w = (char*)d_ws;
  u64* tmp = (u64*)w;       w += (size_t)E_tot * 8;
  u32* pairs = (u32*)w;     w += (size_t)E_tot * 4;
  int* bins = (int*)w;      w += (size_t)(B_TOT + 1) * 4;
  int* bucketHist = (int*)w; w += 512 * 4;
  int* bucketBase = (int*)w; w += (NBUCK + 1) * 4;
  int* cursor = (int*)w;     w += 512 * 4;
  u16* r_d  = (u16*)w;      w += (size_t)N_D * 64 * 2;
  u16* r_a  = (u16*)w;      w += (size_t)N_A * 64 * 2;
  u16* y_md = (u16*)w;      w += (size_t)N_M * 32 * 2;
  u16* y_dm = (u16*)w;      w += (size_t)N_D * 32 * 2;
  u16* y_ma = (u16*)w;      w += (size_t)N_M * 32 * 2;
  u16* y_am = (u16*)w;      w += (size_t)N_A * 32 * 2;
  if ((size_t)(w - (char*)d_ws) > ws_size) return;
  // tables aliasing tmp (written only after phaseB has consumed tmp)
  char* ta = (char*)tmp;
  u16* t_md = (u16*)ta;     ta += (size_t)N_M * 64 * 2;
  u16* t_dm = (u16*)ta;     ta += (size_t)N_D * 64 * 2;
  u16* t_ma = (u16*)ta;     ta += (size_t)N_M * 64 * 2;
  u16* t_am = (u16*)ta;     ta += (size_t)N_A * 64 * 2;
  u16* r_m  = (u16*)ta;     ta += (size_t)N_M * 64 * 2;

  float* o_m = (float*)d_out;
  float* o_d = o_m + (size_t)N_M * 32;
  float* o_a = o_d + (size_t)N_D * 32;

  // ---- bin build: 2-level counting sort ----
  hipMemsetAsync(bucketHist, 0, 512 * 4, stream);

  Rel4 P;
  P.r[0] = { src_md, dst_md, ew_md, E_md, BO_MD, NC_M };
  P.r[1] = { src_dm, dst_dm, ew_dm, E_dm, BO_DM, NC_D };
  P.r[2] = { src_ma, dst_ma, ew_ma, E_ma, BO_MA, NC_M };
  P.r[3] = { src_am, dst_am, ew_am, E_am, BO_AM, NC_A };
  P.blkStart[0] = 0;
  P.blkStart[1] = P.blkStart[0] + nblkA(E_md);
  P.blkStart[2] = P.blkStart[1] + nblkA(E_dm);
  P.blkStart[3] = P.blkStart[2] + nblkA(E_ma);
  P.blkStart[4] = P.blkStart[3] + nblkA(E_am);

  phase0<<<P.blkStart[4], 256, 0, stream>>>(P, bucketHist);
  scan_bucket<<<1, 256, 0, stream>>>(bucketHist, bucketBase, cursor);
  phaseA<<<P.blkStart[4], 256, 0, stream>>>(P, cursor, tmp);
  phaseB<<<NBUCK, 256, 0, stream>>>(tmp, bucketBase, pairs, bins);

  // ---- layer-1 dense transforms (write into tmp-aliased tables) ----
  l1_tr_m<<<768, 256, 0, stream>>>(x_m, W1_rel + 0 * 4096, W1_rel + 2 * 4096,
                                   W1_root + 1 * 4096, W1_root + 3 * 4096,
                                   b1 + 1 * 64, b1 + 3 * 64, t_md, t_ma, r_m, N_M);
  l1_tr_s2<<<1024, 256, 0, stream>>>(
      x_d, W1_rel + 1 * 4096, W1_root + 0 * 4096, b1 + 0 * 64, t_dm, r_d, N_D, 512,
      x_a, W1_rel + 3 * 4096, W1_root + 2 * 4096, b1 + 2 * 64, t_am, r_a, N_A);

  // ---- movie kernel FIRST: produces y_md / y_ma for the merged fused1s ----
  fusedm<<<(N_M + 63) / 64, 512, 0, stream>>>(bins, pairs, t_dm, t_am, r_m,
      W2_rel + 0 * 2048, W2_rel + 2 * 2048, W2_root + 1 * 2048, W2_root + 3 * 2048,
      b2 + 1 * 32, b2 + 3 * 32, y_md, y_ma, o_m, N_M);

  // ---- fused1 per side (stream-serialized -> one 12.8 MB table live) ----
  fused1<<<(N_D + 63) / 64, 512, 0, stream>>>(bins, pairs, t_md, y_md, r_d,
      W2_rel + 1 * 2048, W2_root + 0 * 2048, b2 + 0 * 32, y_dm, o_d, N_D, BO_MD);
  fused1<<<(N_A + 63) / 64, 512, 0, stream>>>(bins, pairs, t_ma, y_ma, r_a,
      W2_rel + 3 * 2048, W2_root + 2 * 2048, b2 + 2 * 32, y_am, o_a, N_A, BO_MA);

  // ---- movie L2 aggregate (needs y_dm / y_am from the fused1s) ----
  outm<<<(N_M + 31) / 32, 256, 0, stream>>>(bins, pairs, y_dm, y_am, o_m, N_M);
}

// Round 9
// 850.421 us; speedup vs baseline: 1.1345x; 1.1345x over previous
//
#include <hip/hip_runtime.h>

#define N_M 100000
#define N_D 30000
#define N_A 80000

// source-chunk binning kept in the SORT ONLY (orders each node's edges by
// 16K-src-chunk); gather kernels consume each node's full adjacency as ONE
// contiguous merged segment (R8's chunk-phasing regressed: short segments).
#define CSHIFT 14
#define NC_M 7   // ceil(100000/16384)
#define NC_D 2   // ceil(30000/16384)
#define NC_A 5   // ceil(80000/16384)

// global bin layout: [md: N_D*NC_M | dm: N_M*NC_D | ma: N_A*NC_M | am: N_M*NC_A]
#define BO_MD 0
#define BO_DM (BO_MD + N_D * NC_M)   // 210000
#define BO_MA (BO_DM + N_M * NC_D)   // 410000
#define BO_AM (BO_MA + N_A * NC_M)   // 970000
#define B_TOT (BO_AM + N_M * NC_A)   // 1470000

// 2-level MSD sort: coarse bucket = key>>12 (359 buckets), fine digit = key&4095
#define FBITS 12
#define NFINE 4096
#define NBUCK ((B_TOT + NFINE - 1) / NFINE)   // 359
#define T_A 4096                              // edges per phase-A block

typedef unsigned int u32;
typedef unsigned short u16;
typedef unsigned long long u64;

__device__ __forceinline__ u16 f2bf(float f) {
  u32 u = __float_as_uint(f);
  return (u16)((u + 0x7FFFu + ((u >> 16) & 1u)) >> 16);
}
__device__ __forceinline__ float bf2f(u16 b) {
  return __uint_as_float(((u32)b) << 16);
}
__device__ __forceinline__ float bf2f_hi(u32 v) {
  return __uint_as_float(v & 0xFFFF0000u);
}
// packed edge: src[31:15] (src<131072), bf16(ew) sans sign in [14:0] (ew>=0)
__device__ __forceinline__ u32 pack_edge(int src, float ew) {
  return ((u32)src << 15) | ((u32)f2bf(ew) & 0x7FFFu);
}

// ===========================================================================
// Bin build: contiguous-write 2-level counting sort
// ===========================================================================
struct Rel { const int* src; const int* dst; const float* ew; int nE; int binBase; int nC; };
struct Rel4 { Rel r[4]; int blkStart[5]; };

__global__ __launch_bounds__(256) void phase0(Rel4 P, int* __restrict__ bucketHist) {
  __shared__ u32 lh[512];
  int tid = threadIdx.x;
  int b = blockIdx.x, s = 0;
  while (b >= P.blkStart[s + 1]) s++;
  const Rel R = P.r[s];
  int base = (b - P.blkStart[s]) * T_A;
  for (int i = tid; i < 512; i += 256) lh[i] = 0;
  __syncthreads();
#pragma unroll 4
  for (int k = 0; k < 16; k++) {
    int e = base + tid + k * 256;
    if (e < R.nE) {
      int key = R.binBase + R.dst[e] * R.nC + (R.src[e] >> CSHIFT);
      atomicAdd(&lh[key >> FBITS], 1u);
    }
  }
  __syncthreads();
  for (int i = tid; i < 512; i += 256) if (lh[i]) atomicAdd(&bucketHist[i], (int)lh[i]);
}

__global__ __launch_bounds__(256) void scan_bucket(const int* __restrict__ bucketHist,
                                                   int* __restrict__ bucketBase,
                                                   int* __restrict__ cursor) {
  __shared__ int wsum[4];
  int tid = threadIdx.x;
  int j0 = tid * 2;
  int a0 = (j0 < NBUCK) ? bucketHist[j0] : 0;
  int a1 = (j0 + 1 < NBUCK) ? bucketHist[j0 + 1] : 0;
  int ssum = a0 + a1;
  int lane = tid & 63, wid = tid >> 6;
  int sc = ssum;
#pragma unroll
  for (int off = 1; off < 64; off <<= 1) { int t = __shfl_up(sc, off, 64); if (lane >= off) sc += t; }
  if (lane == 63) wsum[wid] = sc;
  __syncthreads();
  int wex = 0, tot = 0;
  for (int w = 0; w < 4; w++) { int t = wsum[w]; if (w < wid) wex += t; tot += t; }
  int ex = wex + sc - ssum;
  if (j0 < NBUCK) { bucketBase[j0] = ex; cursor[j0] = ex; }
  if (j0 + 1 < NBUCK) { bucketBase[j0 + 1] = ex + a0; cursor[j0 + 1] = ex + a0; }
  if (tid == 0) bucketBase[NBUCK] = tot;
}

__global__ __launch_bounds__(256) void phaseA(Rel4 P, int* __restrict__ cursor,
                                              u64* __restrict__ tmp) {
  __shared__ u32 hist[512], lstart[512], cur[512], gbase[512];
  __shared__ u64 stage[T_A];
  __shared__ u32 wsum[4];
  int tid = threadIdx.x;
  int b = blockIdx.x, s = 0;
  while (b >= P.blkStart[s + 1]) s++;
  const Rel R = P.r[s];
  int base = (b - P.blkStart[s]) * T_A;
  int valid = min(T_A, R.nE - base);
  for (int i = tid; i < 512; i += 256) hist[i] = 0;
  __syncthreads();
#pragma unroll 4
  for (int k = 0; k < 16; k++) {
    int e = base + tid + k * 256;
    if (e < R.nE) {
      int key = R.binBase + R.dst[e] * R.nC + (R.src[e] >> CSHIFT);
      atomicAdd(&hist[key >> FBITS], 1u);
    }
  }
  __syncthreads();
  int c0 = tid * 2;
  u32 h0 = hist[c0], h1 = hist[c0 + 1];
  u32 ssum = h0 + h1;
  int lane = tid & 63, wid = tid >> 6;
  u32 sc = ssum;
#pragma unroll
  for (int off = 1; off < 64; off <<= 1) { int t = __shfl_up((int)sc, off, 64); if (lane >= off) sc += (u32)t; }
  if (lane == 63) wsum[wid] = sc;
  __syncthreads();
  u32 wex = 0;
  for (int w = 0; w < 4; w++) if (w < wid) wex += wsum[w];
  u32 ex = wex + sc - ssum;
  lstart[c0] = ex;       cur[c0] = ex;
  lstart[c0 + 1] = ex + h0; cur[c0 + 1] = ex + h0;
  if (h0) gbase[c0] = (u32)atomicAdd(&cursor[c0], (int)h0);
  if (h1) gbase[c0 + 1] = (u32)atomicAdd(&cursor[c0 + 1], (int)h1);
  __syncthreads();
#pragma unroll 4
  for (int k = 0; k < 16; k++) {
    int e = base + tid + k * 256;
    if (e < R.nE) {
      int srcv = R.src[e];
      int key = R.binBase + R.dst[e] * R.nC + (srcv >> CSHIFT);
      u32 slot = atomicAdd(&cur[key >> FBITS], 1u);
      stage[slot] = ((u64)(u32)key << 32) | pack_edge(srcv, R.ew[e]);
    }
  }
  __syncthreads();
  for (int i = tid; i < valid; i += 256) {
    u64 v = stage[i];
    u32 c = (u32)(v >> (32 + FBITS));
    tmp[gbase[c] + ((u32)i - lstart[c])] = v;
  }
}

// R9: phaseB at 1024 threads/block (was 256). Only 359 blocks exist (one per
// coarse bucket) -> by construction the old version capped at ~17% of GPU
// thread capacity. 4 digits/thread in the scan (was 16), strides 1024.
__global__ __launch_bounds__(1024) void phaseB(const u64* __restrict__ tmp,
                                               const int* __restrict__ bucketBase,
                                               u32* __restrict__ pairs,
                                               int* __restrict__ bins) {
  __shared__ u32 h2[NFINE], cur2[NFINE];
  __shared__ u32 wsum[16];
  int c = blockIdx.x, tid = threadIdx.x;
  int s0 = bucketBase[c], s1 = bucketBase[c + 1];
  for (int i = tid; i < NFINE; i += 1024) h2[i] = 0;
  __syncthreads();
  for (int e = s0 + tid; e < s1; e += 1024) {
    u32 fine = (u32)(tmp[e] >> 32) & (NFINE - 1);
    atomicAdd(&h2[fine], 1u);
  }
  __syncthreads();
  int f0 = tid * 4;
  u32 v[4], ssum = 0;
#pragma unroll
  for (int i = 0; i < 4; i++) { v[i] = h2[f0 + i]; ssum += v[i]; }
  int lane = tid & 63, wid = tid >> 6;
  u32 sc = ssum;
#pragma unroll
  for (int off = 1; off < 64; off <<= 1) { int t = __shfl_up((int)sc, off, 64); if (lane >= off) sc += (u32)t; }
  if (lane == 63) wsum[wid] = sc;
  __syncthreads();
  u32 wex = 0;
#pragma unroll
  for (int w = 0; w < 16; w++) if (w < wid) wex += wsum[w];
  u32 ex = wex + sc - ssum;
  int binBase0 = c << FBITS;
#pragma unroll
  for (int i = 0; i < 4; i++) {
    int gb = binBase0 + f0 + i;
    if (gb < B_TOT) bins[gb] = s0 + (int)ex;
    cur2[f0 + i] = ex;
    ex += v[i];
  }
  if (c == NBUCK - 1 && tid == 0) bins[B_TOT] = s1;
  __syncthreads();
  for (int e = s0 + tid; e < s1; e += 1024) {
    u64 t = tmp[e];
    u32 fine = (u32)(t >> 32) & (NFINE - 1);
    u32 pos = atomicAdd(&cur2[fine], 1u);
    pairs[s0 + pos] = (u32)t;
  }
}

// ===========================================================================
// Layer-1 dense transforms (unchanged from R7)
// ===========================================================================
__global__ __launch_bounds__(256) void l1_tr_m(
    const float* __restrict__ x,
    const float* __restrict__ Wr0, const float* __restrict__ Wr2,
    const float* __restrict__ Wt1, const float* __restrict__ Wt3,
    const float* __restrict__ b1a, const float* __restrict__ b1b,
    u16* __restrict__ t0, u16* __restrict__ t2, u16* __restrict__ r, int n) {
  __shared__ float A[4096], B[4096], C[4096];
  for (int i = threadIdx.x * 4; i < 4096; i += 1024) {
    *(float4*)&A[i] = *(const float4*)&Wr0[i];
    *(float4*)&B[i] = *(const float4*)&Wr2[i];
    float4 p = *(const float4*)&Wt1[i], q = *(const float4*)&Wt3[i];
    *(float4*)&C[i] = make_float4(p.x + q.x, p.y + q.y, p.z + q.z, p.w + q.w);
  }
  __syncthreads();
  int lane = threadIdx.x & 63, wid = threadIdx.x >> 6;
  int wave = blockIdx.x * 4 + wid, nW = gridDim.x * 4;
  float bj = b1a[lane] + b1b[lane];
  for (int base = wave * 4; base < n; base += nW * 4) {
    int n0 = base, n1 = min(base + 1, n - 1), n2 = min(base + 2, n - 1), n3 = min(base + 3, n - 1);
    float o0a = 0, o0b = 0, o0c = bj, o1a = 0, o1b = 0, o1c = bj;
    float o2a = 0, o2b = 0, o2c = bj, o3a = 0, o3b = 0, o3c = bj;
#pragma unroll 4
    for (int k = 0; k < 64; k++) {
      float wa = A[k * 64 + lane], wb = B[k * 64 + lane], wc = C[k * 64 + lane];
      float x0 = x[(size_t)n0 * 64 + k], x1 = x[(size_t)n1 * 64 + k];
      float x2 = x[(size_t)n2 * 64 + k], x3 = x[(size_t)n3 * 64 + k];
      o0a = fmaf(x0, wa, o0a); o0b = fmaf(x0, wb, o0b); o0c = fmaf(x0, wc, o0c);
      o1a = fmaf(x1, wa, o1a); o1b = fmaf(x1, wb, o1b); o1c = fmaf(x1, wc, o1c);
      o2a = fmaf(x2, wa, o2a); o2b = fmaf(x2, wb, o2b); o2c = fmaf(x2, wc, o2c);
      o3a = fmaf(x3, wa, o3a); o3b = fmaf(x3, wb, o3b); o3c = fmaf(x3, wc, o3c);
    }
    t0[(size_t)n0 * 64 + lane] = f2bf(o0a); t2[(size_t)n0 * 64 + lane] = f2bf(o0b); r[(size_t)n0 * 64 + lane] = f2bf(o0c);
    if (base + 1 < n) { t0[(size_t)n1 * 64 + lane] = f2bf(o1a); t2[(size_t)n1 * 64 + lane] = f2bf(o1b); r[(size_t)n1 * 64 + lane] = f2bf(o1c); }
    if (base + 2 < n) { t0[(size_t)n2 * 64 + lane] = f2bf(o2a); t2[(size_t)n2 * 64 + lane] = f2bf(o2b); r[(size_t)n2 * 64 + lane] = f2bf(o2c); }
    if (base + 3 < n) { t0[(size_t)n3 * 64 + lane] = f2bf(o3a); t2[(size_t)n3 * 64 + lane] = f2bf(o3b); r[(size_t)n3 * 64 + lane] = f2bf(o3c); }
  }
}

__global__ __launch_bounds__(256) void l1_tr_s2(
    const float* __restrict__ x1, const float* __restrict__ Wrel1,
    const float* __restrict__ Wroot1, const float* __restrict__ bias1,
    u16* __restrict__ t1o, u16* __restrict__ r1o, int n1, int nBlk1,
    const float* __restrict__ x2, const float* __restrict__ Wrel2,
    const float* __restrict__ Wroot2, const float* __restrict__ bias2,
    u16* __restrict__ t2o, u16* __restrict__ r2o, int n2) {
  __shared__ float A[4096], C[4096];
  bool first = (int)blockIdx.x < nBlk1;
  const float* x = first ? x1 : x2;
  const float* Wrel = first ? Wrel1 : Wrel2;
  const float* Wroot = first ? Wroot1 : Wroot2;
  const float* bias = first ? bias1 : bias2;
  u16* t = first ? t1o : t2o;
  u16* r = first ? r1o : r2o;
  int n = first ? n1 : n2;
  int blk = first ? blockIdx.x : blockIdx.x - nBlk1;
  int nBlk = first ? nBlk1 : (gridDim.x - nBlk1);
  for (int i = threadIdx.x * 4; i < 4096; i += 1024) {
    *(float4*)&A[i] = *(const float4*)&Wrel[i];
    *(float4*)&C[i] = *(const float4*)&Wroot[i];
  }
  __syncthreads();
  int lane = threadIdx.x & 63, wid = threadIdx.x >> 6;
  int wave = blk * 4 + wid, nW = nBlk * 4;
  float bj = bias[lane];
  for (int base = wave * 4; base < n; base += nW * 4) {
    int n0 = base, n1_ = min(base + 1, n - 1), n2_ = min(base + 2, n - 1), n3_ = min(base + 3, n - 1);
    float o0a = 0, o0c = bj, o1a = 0, o1c = bj, o2a = 0, o2c = bj, o3a = 0, o3c = bj;
#pragma unroll 4
    for (int k = 0; k < 64; k++) {
      float wa = A[k * 64 + lane], wc = C[k * 64 + lane];
      float x0 = x[(size_t)n0 * 64 + k], xx1 = x[(size_t)n1_ * 64 + k];
      float xx2 = x[(size_t)n2_ * 64 + k], xx3 = x[(size_t)n3_ * 64 + k];
      o0a = fmaf(x0, wa, o0a); o0c = fmaf(x0, wc, o0c);
      o1a = fmaf(xx1, wa, o1a); o1c = fmaf(xx1, wc, o1c);
      o2a = fmaf(xx2, wa, o2a); o2c = fmaf(xx2, wc, o2c);
      o3a = fmaf(xx3, wa, o3a); o3c = fmaf(xx3, wc, o3c);
    }
    t[(size_t)n0 * 64 + lane] = f2bf(o0a); r[(size_t)n0 * 64 + lane] = f2bf(o0c);
    if (base + 1 < n) { t[(size_t)n1_ * 64 + lane] = f2bf(o1a); r[(size_t)n1_ * 64 + lane] = f2bf(o1c); }
    if (base + 2 < n) { t[(size_t)n2_ * 64 + lane] = f2bf(o2a); r[(size_t)n2_ * 64 + lane] = f2bf(o2c); }
    if (base + 3 < n) { t[(size_t)n3_ * 64 + lane] = f2bf(o3a); r[(size_t)n3_ * 64 + lane] = f2bf(o3c); }
  }
}

// ===========================================================================
// Gather bodies (R7): 8-edge unroll, XOR/diff routing, zero-pad tails via
// pb = pa & ~0x7FFF.
// ===========================================================================
__device__ __forceinline__ void g2_pair(u32 pa, u32 pb,
    const u16* __restrict__ tbl, u32 lanebyte, u32 hm,
    float& a0, float& a1) {
  u32 offa = (pa >> 15) << 7, offd = ((pb >> 15) << 7) - offa;
  u32 wa = (pa & 0x7FFFu) << 16, wd = ((pb & 0x7FFFu) << 16) ^ wa;
  u32 v = *(const u32*)((const char*)tbl + ((hm & offd) + offa + lanebyte));
  float w = __uint_as_float((hm & wd) ^ wa);
  a0 = fmaf(w, bf2f((u16)v), a0);
  a1 = fmaf(w, bf2f_hi(v), a1);
}

__device__ __forceinline__ void g2y_pair(u32 pa, u32 pb,
    const u16* __restrict__ tbl, const u16* __restrict__ ytbl,
    u32 lanebyte, u32 ylanebyte, u32 hm,
    float& a0, float& a1, float& ay) {
  u32 ra = pa >> 15, rb = pb >> 15;
  u32 offa = ra << 7, offd = (rb << 7) - offa;
  u32 yoa = ra << 6,  yod = (rb << 6) - yoa;
  u32 wa = (pa & 0x7FFFu) << 16, wd = ((pb & 0x7FFFu) << 16) ^ wa;
  u32 v = *(const u32*)((const char*)tbl + ((hm & offd) + offa + lanebyte));
  u16 q = *(const u16*)((const char*)ytbl + ((hm & yod) + yoa + ylanebyte));
  float w = __uint_as_float((hm & wd) ^ wa);
  a0 = fmaf(w, bf2f((u16)v), a0);
  a1 = fmaf(w, bf2f_hi(v), a1);
  ay = fmaf(w, bf2f(q), ay);
}

#define RL(x, i) ((u32)__builtin_amdgcn_readlane((int)(x), (i)))

__device__ __forceinline__ void gather2_seg64(
    int s0, int s1, const u32* __restrict__ pairs,
    const u16* __restrict__ tbl, u32 lanebyte, u32 hm, int lane, u32 pw0,
    float& a0, float& a1) {
  int base = s0;
  u32 pw = pw0;
  for (;;) {
    int cnt = s1 - base; if (cnt > 64) cnt = 64;
    int e = 0;
    for (; e + 8 <= cnt; e += 8) {
      u32 p0 = RL(pw, e),     p1 = RL(pw, e + 1), p2 = RL(pw, e + 2), p3 = RL(pw, e + 3);
      u32 p4 = RL(pw, e + 4), p5 = RL(pw, e + 5), p6 = RL(pw, e + 6), p7 = RL(pw, e + 7);
      g2_pair(p0, p1, tbl, lanebyte, hm, a0, a1);
      g2_pair(p2, p3, tbl, lanebyte, hm, a0, a1);
      g2_pair(p4, p5, tbl, lanebyte, hm, a0, a1);
      g2_pair(p6, p7, tbl, lanebyte, hm, a0, a1);
    }
    if (e + 4 <= cnt) {
      u32 p0 = RL(pw, e), p1 = RL(pw, e + 1), p2 = RL(pw, e + 2), p3 = RL(pw, e + 3);
      g2_pair(p0, p1, tbl, lanebyte, hm, a0, a1);
      g2_pair(p2, p3, tbl, lanebyte, hm, a0, a1);
      e += 4;
    }
    if (e + 2 <= cnt) {
      u32 p0 = RL(pw, e), p1 = RL(pw, e + 1);
      g2_pair(p0, p1, tbl, lanebyte, hm, a0, a1);
      e += 2;
    }
    if (e < cnt) {
      u32 p = RL(pw, e);
      g2_pair(p, p & 0xFFFF8000u, tbl, lanebyte, hm, a0, a1);
    }
    base += 64;
    if (base >= s1) break;
    pw = (base + lane < s1) ? pairs[base + lane] : 0u;
  }
}

__device__ __forceinline__ void gather2y_seg64(
    int s0, int s1, const u32* __restrict__ pairs,
    const u16* __restrict__ tbl, const u16* __restrict__ ytbl,
    u32 lanebyte, u32 ylanebyte, u32 hm, int lane, u32 pw0,
    float& a0, float& a1, float& ay) {
  int base = s0;
  u32 pw = pw0;
  for (;;) {
    int cnt = s1 - base; if (cnt > 64) cnt = 64;
    int e = 0;
    for (; e + 8 <= cnt; e += 8) {
      u32 p0 = RL(pw, e),     p1 = RL(pw, e + 1), p2 = RL(pw, e + 2), p3 = RL(pw, e + 3);
      u32 p4 = RL(pw, e + 4), p5 = RL(pw, e + 5), p6 = RL(pw, e + 6), p7 = RL(pw, e + 7);
      g2y_pair(p0, p1, tbl, ytbl, lanebyte, ylanebyte, hm, a0, a1, ay);
      g2y_pair(p2, p3, tbl, ytbl, lanebyte, ylanebyte, hm, a0, a1, ay);
      g2y_pair(p4, p5, tbl, ytbl, lanebyte, ylanebyte, hm, a0, a1, ay);
      g2y_pair(p6, p7, tbl, ytbl, lanebyte, ylanebyte, hm, a0, a1, ay);
    }
    if (e + 4 <= cnt) {
      u32 p0 = RL(pw, e), p1 = RL(pw, e + 1), p2 = RL(pw, e + 2), p3 = RL(pw, e + 3);
      g2y_pair(p0, p1, tbl, ytbl, lanebyte, ylanebyte, hm, a0, a1, ay);
      g2y_pair(p2, p3, tbl, ytbl, lanebyte, ylanebyte, hm, a0, a1, ay);
      e += 4;
    }
    if (e + 2 <= cnt) {
      u32 p0 = RL(pw, e), p1 = RL(pw, e + 1);
      g2y_pair(p0, p1, tbl, ytbl, lanebyte, ylanebyte, hm, a0, a1, ay);
      e += 2;
    }
    if (e < cnt) {
      u32 p = RL(pw, e);
      g2y_pair(p, p & 0xFFFF8000u, tbl, ytbl, lanebyte, ylanebyte, hm, a0, a1, ay);
    }
    base += 64;
    if (base >= s1) break;
    pw = (base + lane < s1) ? pairs[base + lane] : 0u;
  }
}

// ===========================================================================
// 32-wide gather (outm only): unchanged.
// ===========================================================================
__device__ __forceinline__ void gathero_32(
    int s0, int s1, const u32* __restrict__ pairs,
    const u16* __restrict__ ytbl, int lanebyte, int oaddr, int lane,
    float& a0, float& a1, float& a2, float& a3) {
  for (int base = s0; base < s1; base += 64) {
    u32 pw = 0;
    if (base + lane < s1) pw = pairs[base + lane];
    int ng = min(s1 - base, 64);
    ng = (ng + 7) >> 3;
#pragma unroll 2
    for (int g = 0; g < ng; g++) {
      u32 p = (u32)__builtin_amdgcn_ds_bpermute(oaddr + (g << 5), (int)pw);
      u32 off = ((p >> 15) << 6) + lanebyte;
      float w = __uint_as_float((p & 0x7FFFu) << 16);
      uint2 v = *(const uint2*)((const char*)ytbl + off);
      a0 = fmaf(w, bf2f((u16)v.x), a0);
      a1 = fmaf(w, bf2f_hi(v.x), a1);
      a2 = fmaf(w, bf2f((u16)v.y), a2);
      a3 = fmaf(w, bf2f_hi(v.y), a3);
    }
  }
}

// Merged fused1 for BOTH director and actor sides in one dispatch (R7).
struct F1Side {
  const u16 *tbl, *ytbl, *r1;
  const float *W2r, *W2t, *b2;
  u16 *y; float *out;
  int n, nC, binBase;
};

__global__ __launch_bounds__(512) void fused1(
    const int* __restrict__ bins, const u32* __restrict__ pairs,
    F1Side D, F1Side A, int nBlkD) {
  __shared__ float Wy[2048], Wt[2048];
  __shared__ float bs[32];
  __shared__ __align__(16) float scr[8][64];
  bool isD = (int)blockIdx.x < nBlkD;
  F1Side S = isD ? D : A;
  int blk = isD ? blockIdx.x : blockIdx.x - nBlkD;
  for (int i = threadIdx.x; i < 2048; i += 512) { Wy[i] = S.W2r[i]; Wt[i] = S.W2t[i]; }
  if (threadIdx.x < 32) bs[threadIdx.x] = S.b2[threadIdx.x];
  __syncthreads();
  int lane = threadIdx.x & 63, wid = threadIdx.x >> 6;
  int j = lane & 31, half = lane >> 5;
  u32 lanebyte = (u32)j << 2;
  u32 ylanebyte = (u32)j << 1;
  u32 hm = half ? 0xFFFFFFFFu : 0u;
  int node0 = (blk * 8 + wid) * 8;
  int bnd = bins[S.binBase + min(node0 + min(lane, 8), S.n) * S.nC];
  float acc0[8], acc1[8], accy[8];
#pragma unroll
  for (int i = 0; i < 8; i++) { acc0[i] = 0.f; acc1[i] = 0.f; accy[i] = 0.f; }
  // batched first-window pair prefetch (8 independent loads in flight)
  u32 pwp[8];
#pragma unroll
  for (int i = 0; i < 8; i++) {
    int s0 = __builtin_amdgcn_readlane(bnd, i);
    int s1 = __builtin_amdgcn_readlane(bnd, i + 1);
    pwp[i] = (node0 + i < S.n && s0 + lane < s1) ? pairs[s0 + lane] : 0u;
  }
#pragma unroll
  for (int i = 0; i < 8; i++) {
    int s0 = __builtin_amdgcn_readlane(bnd, i);
    int s1 = __builtin_amdgcn_readlane(bnd, i + 1);
    if (node0 + i < S.n && s0 < s1)
      gather2y_seg64(s0, s1, pairs, S.tbl, S.ytbl, lanebyte, ylanebyte, hm, lane, pwp[i],
                     acc0[i], acc1[i], accy[i]);
  }
#pragma unroll
  for (int i = 0; i < 8; i++) {
    int node = node0 + i;
    if (node >= S.n) continue;
    float a0 = acc0[i] + __shfl_xor(acc0[i], 32);
    float a1 = acc1[i] + __shfl_xor(acc1[i], 32);
    float ayt = accy[i] + __shfl_xor(accy[i], 32);
    u32 rv = *(const u32*)&S.r1[(size_t)node * 64 + 2 * j];
    float hv0 = fmaxf(a0 + bf2f((u16)rv), 0.f);
    float hv1 = fmaxf(a1 + bf2f_hi(rv), 0.f);
    if (!half) *(float2*)&scr[wid][2 * j] = make_float2(hv0, hv1);
    float oy = 0.f, ot = 0.f;
#pragma unroll
    for (int kk = 0; kk < 32; kk++) {
      int k = (half << 5) + kk;
      float s = scr[wid][k];
      oy = fmaf(s, Wy[k * 32 + j], oy);
      ot = fmaf(s, Wt[k * 32 + j], ot);
    }
    oy += __shfl_xor(oy, 32);
    ot += __shfl_xor(ot, 32);
    if (lane < 32) {
      S.y[(size_t)node * 32 + lane] = f2bf(oy);
      S.out[(size_t)node * 32 + lane] = ot + bs[lane] + ayt;
    }
  }
}

// Movie variant (R7): both relations merged, full segments. Runs FIRST.
__global__ __launch_bounds__(512) void fusedm(
    const int* __restrict__ bins, const u32* __restrict__ pairs,
    const u16* __restrict__ tbl1,   // t_dm (director rows)
    const u16* __restrict__ tbl2,   // t_am (actor rows)
    const u16* __restrict__ r1,
    const float* __restrict__ W2r0, const float* __restrict__ W2r2,
    const float* __restrict__ W2t1, const float* __restrict__ W2t3,
    const float* __restrict__ b2a, const float* __restrict__ b2b,
    u16* __restrict__ y0, u16* __restrict__ y2, float* __restrict__ oroot, int n) {
  __shared__ float Wy0[2048], Wy2[2048], Wt[2048];
  __shared__ float bs[32];
  __shared__ __align__(16) float scr[8][64];
  for (int i = threadIdx.x; i < 2048; i += 512) {
    Wy0[i] = W2r0[i]; Wy2[i] = W2r2[i]; Wt[i] = W2t1[i] + W2t3[i];
  }
  if (threadIdx.x < 32) bs[threadIdx.x] = b2a[threadIdx.x] + b2b[threadIdx.x];
  __syncthreads();
  int lane = threadIdx.x & 63, wid = threadIdx.x >> 6;
  int j = lane & 31, half = lane >> 5;
  u32 lanebyte = (u32)j << 2;
  u32 hm = half ? 0xFFFFFFFFu : 0u;
  int node0 = (blockIdx.x * 8 + wid) * 8;
  int bdm = bins[BO_DM + min(node0 + min(lane, 8), n) * NC_D];
  int bam = bins[BO_AM + min(node0 + min(lane, 8), n) * NC_A];
  float acc0[8], acc1[8];
#pragma unroll
  for (int i = 0; i < 8; i++) { acc0[i] = 0.f; acc1[i] = 0.f; }
  {
    u32 pwp[8];
#pragma unroll
    for (int i = 0; i < 8; i++) {
      int s0 = __builtin_amdgcn_readlane(bdm, i);
      int s1 = __builtin_amdgcn_readlane(bdm, i + 1);
      pwp[i] = (node0 + i < n && s0 + lane < s1) ? pairs[s0 + lane] : 0u;
    }
#pragma unroll
    for (int i = 0; i < 8; i++) {
      int s0 = __builtin_amdgcn_readlane(bdm, i);
      int s1 = __builtin_amdgcn_readlane(bdm, i + 1);
      if (node0 + i < n && s0 < s1)
        gather2_seg64(s0, s1, pairs, tbl1, lanebyte, hm, lane, pwp[i], acc0[i], acc1[i]);
    }
  }
  {
    u32 pwp[8];
#pragma unroll
    for (int i = 0; i < 8; i++) {
      int s0 = __builtin_amdgcn_readlane(bam, i);
      int s1 = __builtin_amdgcn_readlane(bam, i + 1);
      pwp[i] = (node0 + i < n && s0 + lane < s1) ? pairs[s0 + lane] : 0u;
    }
#pragma unroll
    for (int i = 0; i < 8; i++) {
      int s0 = __builtin_amdgcn_readlane(bam, i);
      int s1 = __builtin_amdgcn_readlane(bam, i + 1);
      if (node0 + i < n && s0 < s1)
        gather2_seg64(s0, s1, pairs, tbl2, lanebyte, hm, lane, pwp[i], acc0[i], acc1[i]);
    }
  }
#pragma unroll
  for (int i = 0; i < 8; i++) {
    int node = node0 + i;
    if (node >= n) continue;
    float a0 = acc0[i] + __shfl_xor(acc0[i], 32);
    float a1 = acc1[i] + __shfl_xor(acc1[i], 32);
    u32 rv = *(const u32*)&r1[(size_t)node * 64 + 2 * j];
    float hv0 = fmaxf(a0 + bf2f((u16)rv), 0.f);
    float hv1 = fmaxf(a1 + bf2f_hi(rv), 0.f);
    if (!half) *(float2*)&scr[wid][2 * j] = make_float2(hv0, hv1);
    float o0 = 0.f, o2 = 0.f, ot = 0.f;
#pragma unroll
    for (int kk = 0; kk < 32; kk++) {
      int k = (half << 5) + kk;
      float s = scr[wid][k];
      o0 = fmaf(s, Wy0[k * 32 + j], o0);
      o2 = fmaf(s, Wy2[k * 32 + j], o2);
      ot = fmaf(s, Wt[k * 32 + j], ot);
    }
    o0 += __shfl_xor(o0, 32);
    o2 += __shfl_xor(o2, 32);
    ot += __shfl_xor(ot, 32);
    if (lane < 32) {
      y0[(size_t)node * 32 + lane] = f2bf(o0);
      y2[(size_t)node * 32 + lane] = f2bf(o2);
      oroot[(size_t)node * 32 + lane] = ot + bs[lane];
    }
  }
}

__global__ __launch_bounds__(256) void outm(
    const int* __restrict__ bins, const u32* __restrict__ pairs,
    const u16* __restrict__ y1,   // y_dm (director rows)
    const u16* __restrict__ y2,   // y_am (actor rows)
    float* __restrict__ out, int n) {
  int lane = threadIdx.x & 63, wid = threadIdx.x >> 6;
  int node0 = (blockIdx.x * 4 + wid) * 8;
  int j8 = lane & 7;
  int lanebyte = j8 << 3;
  int oaddr = (lane >> 3) << 2;
  int bdm = bins[BO_DM + min(node0 + min(lane, 8), n) * NC_D];
  int bam = bins[BO_AM + min(node0 + min(lane, 8), n) * NC_A];
  float acc0[8], acc1[8], acc2[8], acc3[8];
#pragma unroll
  for (int i = 0; i < 8; i++) { acc0[i] = 0.f; acc1[i] = 0.f; acc2[i] = 0.f; acc3[i] = 0.f; }
#pragma unroll
  for (int i = 0; i < 8; i++) {
    int s0 = __builtin_amdgcn_readlane(bdm, i);
    int s1 = __builtin_amdgcn_readlane(bdm, i + 1);
    if (node0 + i < n) gathero_32(s0, s1, pairs, y1, lanebyte, oaddr, lane,
                                  acc0[i], acc1[i], acc2[i], acc3[i]);
  }
#pragma unroll
  for (int i = 0; i < 8; i++) {
    int s0 = __builtin_amdgcn_readlane(bam, i);
    int s1 = __builtin_amdgcn_readlane(bam, i + 1);
    if (node0 + i < n) gathero_32(s0, s1, pairs, y2, lanebyte, oaddr, lane,
                                  acc0[i], acc1[i], acc2[i], acc3[i]);
  }
#pragma unroll
  for (int i = 0; i < 8; i++) {
    int node = node0 + i;
    if (node >= n) continue;
    float a0 = acc0[i], a1 = acc1[i], a2 = acc2[i], a3 = acc3[i];
    a0 += __shfl_xor(a0, 8); a0 += __shfl_xor(a0, 16); a0 += __shfl_xor(a0, 32);
    a1 += __shfl_xor(a1, 8); a1 += __shfl_xor(a1, 16); a1 += __shfl_xor(a1, 32);
    a2 += __shfl_xor(a2, 8); a2 += __shfl_xor(a2, 16); a2 += __shfl_xor(a2, 32);
    a3 += __shfl_xor(a3, 8); a3 += __shfl_xor(a3, 16); a3 += __shfl_xor(a3, 32);
    if (lane < 8) {
      float4* o = (float4*)((char*)out + (size_t)node * 128 + (j8 << 4));
      float4 v = *o;
      v.x += a0; v.y += a1; v.z += a2; v.w += a3;
      *o = v;
    }
  }
}

static inline int nblkA(long long e) { return (int)((e + T_A - 1) / T_A); }

extern "C" void kernel_launch(void* const* d_in, const int* in_sizes, int n_in,
                              void* d_out, int out_size, void* d_ws, size_t ws_size,
                              hipStream_t stream) {
  const float* x_m = (const float*)d_in[0];
  const float* x_d = (const float*)d_in[1];
  const float* x_a = (const float*)d_in[2];
  const int* src_md = (const int*)d_in[3];
  const int* dst_md = (const int*)d_in[4];
  const float* ew_md = (const float*)d_in[5];
  const int* src_dm = (const int*)d_in[6];
  const int* dst_dm = (const int*)d_in[7];
  const float* ew_dm = (const float*)d_in[8];
  const int* src_ma = (const int*)d_in[9];
  const int* dst_ma = (const int*)d_in[10];
  const float* ew_ma = (const float*)d_in[11];
  const int* src_am = (const int*)d_in[12];
  const int* dst_am = (const int*)d_in[13];
  const float* ew_am = (const float*)d_in[14];
  const float* W1_rel = (const float*)d_in[15];
  const float* b1 = (const float*)d_in[16];
  const float* W1_root = (const float*)d_in[17];
  const float* W2_rel = (const float*)d_in[18];
  const float* b2 = (const float*)d_in[19];
  const float* W2_root = (const float*)d_in[20];

  const int E_md = in_sizes[3];
  const int E_dm = in_sizes[6];
  const int E_ma = in_sizes[9];
  const int E_am = in_sizes[12];
  const long long E_tot = (long long)E_md + E_dm + E_ma + E_am;

  // ---- workspace ----
  char* w = (char*)d_ws;
  u64* tmp = (u64*)w;       w += (size_t)E_tot * 8;
  u32* pairs = (u32*)w;     w += (size_t)E_tot * 4;
  int* bins = (int*)w;      w += (size_t)(B_TOT + 1) * 4;
  int* bucketHist = (int*)w; w += 512 * 4;
  int* bucketBase = (int*)w; w += (NBUCK + 1) * 4;
  int* cursor = (int*)w;     w += 512 * 4;
  u16* r_d  = (u16*)w;      w += (size_t)N_D * 64 * 2;
  u16* r_a  = (u16*)w;      w += (size_t)N_A * 64 * 2;
  u16* y_md = (u16*)w;      w += (size_t)N_M * 32 * 2;
  u16* y_dm = (u16*)w;      w += (size_t)N_D * 32 * 2;
  u16* y_ma = (u16*)w;      w += (size_t)N_M * 32 * 2;
  u16* y_am = (u16*)w;      w += (size_t)N_A * 32 * 2;
  if ((size_t)(w - (char*)d_ws) > ws_size) return;
  // tables aliasing tmp (written only after phaseB has consumed tmp)
  char* ta = (char*)tmp;
  u16* t_md = (u16*)ta;     ta += (size_t)N_M * 64 * 2;
  u16* t_dm = (u16*)ta;     ta += (size_t)N_D * 64 * 2;
  u16* t_ma = (u16*)ta;     ta += (size_t)N_M * 64 * 2;
  u16* t_am = (u16*)ta;     ta += (size_t)N_A * 64 * 2;
  u16* r_m  = (u16*)ta;     ta += (size_t)N_M * 64 * 2;

  float* o_m = (float*)d_out;
  float* o_d = o_m + (size_t)N_M * 32;
  float* o_a = o_d + (size_t)N_D * 32;

  // ---- bin build: 2-level counting sort ----
  hipMemsetAsync(bucketHist, 0, 512 * 4, stream);

  Rel4 P;
  P.r[0] = { src_md, dst_md, ew_md, E_md, BO_MD, NC_M };
  P.r[1] = { src_dm, dst_dm, ew_dm, E_dm, BO_DM, NC_D };
  P.r[2] = { src_ma, dst_ma, ew_ma, E_ma, BO_MA, NC_M };
  P.r[3] = { src_am, dst_am, ew_am, E_am, BO_AM, NC_A };
  P.blkStart[0] = 0;
  P.blkStart[1] = P.blkStart[0] + nblkA(E_md);
  P.blkStart[2] = P.blkStart[1] + nblkA(E_dm);
  P.blkStart[3] = P.blkStart[2] + nblkA(E_ma);
  P.blkStart[4] = P.blkStart[3] + nblkA(E_am);

  phase0<<<P.blkStart[4], 256, 0, stream>>>(P, bucketHist);
  scan_bucket<<<1, 256, 0, stream>>>(bucketHist, bucketBase, cursor);
  phaseA<<<P.blkStart[4], 256, 0, stream>>>(P, cursor, tmp);
  phaseB<<<NBUCK, 1024, 0, stream>>>(tmp, bucketBase, pairs, bins);

  // ---- layer-1 dense transforms (write into tmp-aliased tables) ----
  l1_tr_m<<<768, 256, 0, stream>>>(x_m, W1_rel + 0 * 4096, W1_rel + 2 * 4096,
                                   W1_root + 1 * 4096, W1_root + 3 * 4096,
                                   b1 + 1 * 64, b1 + 3 * 64, t_md, t_ma, r_m, N_M);
  l1_tr_s2<<<1024, 256, 0, stream>>>(
      x_d, W1_rel + 1 * 4096, W1_root + 0 * 4096, b1 + 0 * 64, t_dm, r_d, N_D, 512,
      x_a, W1_rel + 3 * 4096, W1_root + 2 * 4096, b1 + 2 * 64, t_am, r_a, N_A);

  // ---- movie kernel FIRST: produces y_md / y_ma for the merged fused1s ----
  fusedm<<<(N_M + 63) / 64, 512, 0, stream>>>(bins, pairs, t_dm, t_am, r_m,
      W2_rel + 0 * 2048, W2_rel + 2 * 2048, W2_root + 1 * 2048, W2_root + 3 * 2048,
      b2 + 1 * 32, b2 + 3 * 32, y_md, y_ma, o_m, N_M);

  // ---- merged fused1 (D + A in one dispatch): L1+L2 gathers in one pass ----
  int nBlkD = (N_D + 63) / 64;
  int nBlkA_ = (N_A + 63) / 64;
  F1Side Dside = { t_md, y_md, r_d, W2_rel + 1 * 2048, W2_root + 0 * 2048, b2 + 0 * 32,
                   y_dm, o_d, N_D, NC_M, BO_MD };
  F1Side Aside = { t_ma, y_ma, r_a, W2_rel + 3 * 2048, W2_root + 2 * 2048, b2 + 2 * 32,
                   y_am, o_a, N_A, NC_M, BO_MA };
  fused1<<<nBlkD + nBlkA_, 512, 0, stream>>>(bins, pairs, Dside, Aside, nBlkD);

  // ---- movie L2 aggregate (needs y_dm / y_am from the fused1s) ----
  outm<<<(N_M + 31) / 32, 256, 0, stream>>>(bins, pairs, y_dm, y_am, o_m, N_M);
}